// Round 4
// baseline (231.420 us; speedup 1.0000x reference)
//
#include <hip/hip_runtime.h>

// SO2Linear: out[n, M_out[e], c] += x[n, M_in[e], c] * weight[w_idx[e], c] * sign[e]
// L_MAX=6 -> 49 orders, 413 entries, 231 weights. N=2048, C=256.
// Round 4: no LDS, no barrier (working set is L2/L3-resident; staging was
// serializing). Weights pre-expanded (sign folded, entry-ordered) into d_ws
// so main-loop weight reads are sequential. Entry table fully unrolled to
// immediates.

#define LMAX 6
#define NORD 49            // (LMAX+1)^2
#define NENT 413
#define NWGT 231
#define C4   64            // C/4 float4 lanes
#define NW   8             // waves per block
#define BLK  512

struct Meta {
  unsigned packed[NENT];   // m_in | (w_idx<<8) | (sign_bit<<31), sorted by (i_out, i_in)
  int gstart[NORD + 1];    // entry range per i_out group
  int wbeg[NW + 1];        // group-range boundaries for the NW waves of a block
};

constexpr Meta make_meta() {
  Meta m{};
  int io[NENT] = {}, ii[NENT] = {}, wi[NENT] = {}, sg[NENT] = {};
  int cnt = 0, widx = 0;
  for (int lo = 0; lo <= LMAX; ++lo) {
    for (int li = 0; li <= LMAX; ++li) {
      int mn = lo < li ? lo : li;
      for (int mw = -mn; mw <= mn; ++mw) {
        if (mw == 0) {
          io[cnt] = lo * lo + lo; ii[cnt] = li * li + li;
          wi[cnt] = widx; sg[cnt] = 0; ++cnt;
        } else {
          int a = mw > 0 ? mw : -mw;
          io[cnt] = lo * lo + lo - a; ii[cnt] = li * li + li - mw;
          wi[cnt] = widx; sg[cnt] = 0; ++cnt;
          io[cnt] = lo * lo + lo + a; ii[cnt] = li * li + li + mw;
          wi[cnt] = widx; sg[cnt] = (mw < 0) ? 1 : 0; ++cnt;
        }
        ++widx;
      }
    }
  }
  // Sort by (i_out, i_in): keys unique -> bucket sort.
  int slot[NORD * NORD];
  for (int k = 0; k < NORD * NORD; ++k) slot[k] = -1;
  for (int e = 0; e < cnt; ++e) slot[io[e] * NORD + ii[e]] = e;
  int order[NENT] = {};
  int s = 0;
  for (int k = 0; k < NORD * NORD; ++k)
    if (slot[k] >= 0) order[s++] = slot[k];
  int gc[NORD] = {};
  for (int e = 0; e < cnt; ++e) gc[io[e]]++;
  m.gstart[0] = 0;
  for (int g = 0; g < NORD; ++g) m.gstart[g + 1] = m.gstart[g] + gc[g];
  for (int t = 0; t < cnt; ++t) {
    int e = order[t];
    m.packed[t] = (unsigned)ii[e] | ((unsigned)wi[e] << 8) | ((unsigned)sg[e] << 31);
  }
  // NW-way partition of the 49 groups, balanced by entry count.
  m.wbeg[0] = 0; m.wbeg[NW] = NORD;
  for (int y = 1; y < NW; ++y) {
    int target = (cnt * y) / NW;
    int g = m.wbeg[y - 1] + 1;
    while (g < NORD && m.gstart[g] < target) ++g;
    if (g - 1 > m.wbeg[y - 1] &&
        (m.gstart[g] - target) > (target - m.gstart[g - 1])) --g;
    int maxg = NORD - (NW - y);
    if (g > maxg) g = maxg;
    m.wbeg[y] = g;
  }
  return m;
}

static constexpr Meta g_meta = make_meta();
__constant__ Meta c_meta = make_meta();   // runtime-indexed copy for pre-kernel

// ---- weight expansion: wexp[e, :] = sign[e] * weight[w_idx[e], :] ----
__global__ __launch_bounds__(256) void so2_expand_w(
    const float* __restrict__ w, float* __restrict__ wexp) {
  const int e = blockIdx.x * 4 + (threadIdx.x >> 6);
  const int lane = threadIdx.x & 63;
  if (e >= NENT) return;
  const unsigned p = c_meta.packed[e];
  const int wix = (int)((p >> 8) & 0x3FFu);
  const unsigned sbit = p & 0x80000000u;
  float4 v = reinterpret_cast<const float4*>(w)[wix * C4 + lane];
  v.x = __uint_as_float(__float_as_uint(v.x) ^ sbit);
  v.y = __uint_as_float(__float_as_uint(v.y) ^ sbit);
  v.z = __uint_as_float(__float_as_uint(v.z) ^ sbit);
  v.w = __uint_as_float(__float_as_uint(v.w) ^ sbit);
  reinterpret_cast<float4*>(wexp)[e * C4 + lane] = v;
}

// ---- fully-unrolled entry chain: all indices immediates; loads global ----
template <bool XW, int E, int E1>
struct Ent {
  __device__ static inline void run(float4& acc, const float4* __restrict__ xg,
                                    const float4* __restrict__ wp, int lane) {
    constexpr unsigned p = g_meta.packed[E];
    constexpr int mi = (int)(p & 255u);
    float4 xv = xg[mi * C4 + lane];               // L1/L2-hit, coalesced 1KB/wave
    if constexpr (XW) {
      float4 wv = wp[E * C4 + lane];              // sequential expanded weights
      acc.x = fmaf(xv.x, wv.x, acc.x);
      acc.y = fmaf(xv.y, wv.y, acc.y);
      acc.z = fmaf(xv.z, wv.z, acc.z);
      acc.w = fmaf(xv.w, wv.w, acc.w);
    } else {
      constexpr int wix = (int)((p >> 8) & 0x3FFu);
      constexpr bool neg = (p & 0x80000000u) != 0u;
      float4 wv = wp[wix * C4 + lane];
      if constexpr (neg) {
        acc.x = fmaf(-xv.x, wv.x, acc.x);
        acc.y = fmaf(-xv.y, wv.y, acc.y);
        acc.z = fmaf(-xv.z, wv.z, acc.z);
        acc.w = fmaf(-xv.w, wv.w, acc.w);
      } else {
        acc.x = fmaf(xv.x, wv.x, acc.x);
        acc.y = fmaf(xv.y, wv.y, acc.y);
        acc.z = fmaf(xv.z, wv.z, acc.z);
        acc.w = fmaf(xv.w, wv.w, acc.w);
      }
    }
    Ent<XW, E + 1, E1>::run(acc, xg, wp, lane);
  }
};
template <bool XW, int E1>
struct Ent<XW, E1, E1> {
  __device__ static inline void run(float4&, const float4*, const float4*, int) {}
};

template <bool XW, int G, int G1>
struct Grp {
  __device__ static inline void run(const float4* __restrict__ xg,
                                    const float4* __restrict__ wp,
                                    float4* __restrict__ og, int lane) {
    float4 acc = make_float4(0.f, 0.f, 0.f, 0.f);
    Ent<XW, g_meta.gstart[G], g_meta.gstart[G + 1]>::run(acc, xg, wp, lane);
    og[G * C4 + lane] = acc;                       // each float4 written exactly once
    Grp<XW, G + 1, G1>::run(xg, wp, og, lane);
  }
};
template <bool XW, int G1>
struct Grp<XW, G1, G1> {
  __device__ static inline void run(const float4*, const float4*, float4*, int) {}
};

template <bool XW>
__global__ __launch_bounds__(BLK) void so2_kernel(
    const float* __restrict__ x, const float* __restrict__ wp_,
    float* __restrict__ out) {
  const int tid = threadIdx.x;
  const int n = blockIdx.x;
  const int wv = tid >> 6;
  const int lane = tid & 63;

  const float4* __restrict__ xg =
      reinterpret_cast<const float4*>(x) + (size_t)n * (NORD * C4);
  const float4* __restrict__ wp = reinterpret_cast<const float4*>(wp_);
  float4* __restrict__ og =
      reinterpret_cast<float4*>(out) + (size_t)n * (NORD * C4);

  switch (wv) {
    case 0: Grp<XW, g_meta.wbeg[0], g_meta.wbeg[1]>::run(xg, wp, og, lane); break;
    case 1: Grp<XW, g_meta.wbeg[1], g_meta.wbeg[2]>::run(xg, wp, og, lane); break;
    case 2: Grp<XW, g_meta.wbeg[2], g_meta.wbeg[3]>::run(xg, wp, og, lane); break;
    case 3: Grp<XW, g_meta.wbeg[3], g_meta.wbeg[4]>::run(xg, wp, og, lane); break;
    case 4: Grp<XW, g_meta.wbeg[4], g_meta.wbeg[5]>::run(xg, wp, og, lane); break;
    case 5: Grp<XW, g_meta.wbeg[5], g_meta.wbeg[6]>::run(xg, wp, og, lane); break;
    case 6: Grp<XW, g_meta.wbeg[6], g_meta.wbeg[7]>::run(xg, wp, og, lane); break;
    case 7: Grp<XW, g_meta.wbeg[7], g_meta.wbeg[8]>::run(xg, wp, og, lane); break;
  }
}

extern "C" void kernel_launch(void* const* d_in, const int* in_sizes, int n_in,
                              void* d_out, int out_size, void* d_ws, size_t ws_size,
                              hipStream_t stream) {
  const float* x = (const float*)d_in[0];
  const float* w = (const float*)d_in[1];
  float* out = (float*)d_out;
  const int n_rows = in_sizes[0] / (NORD * 4 * C4);  // = 2048
  const size_t need = (size_t)NENT * C4 * sizeof(float4);  // 423 KB
  if (ws_size >= need) {
    float* wexp = (float*)d_ws;
    so2_expand_w<<<(NENT + 3) / 4, 256, 0, stream>>>(w, wexp);
    so2_kernel<true><<<n_rows, BLK, 0, stream>>>(x, wexp, out);
  } else {
    so2_kernel<false><<<n_rows, BLK, 0, stream>>>(x, w, out);
  }
}